// Round 2
// baseline (15995.271 us; speedup 1.0000x reference)
//
#include <hip/hip_runtime.h>
#include <hip/hip_bf16.h>

#define B 512
#define S 64
#define H 1024
#define O 1024
#define T 128
#define ATT 64

typedef __bf16 bf16;
typedef __bf16 bf16x8 __attribute__((ext_vector_type(8)));
typedef __bf16 bf16x4 __attribute__((ext_vector_type(4)));
typedef float f32x4 __attribute__((ext_vector_type(4)));

static __device__ __forceinline__ float bf2f(bf16 b) {
    unsigned short s = __builtin_bit_cast(unsigned short, b);
    unsigned int u = ((unsigned int)s) << 16;
    return __builtin_bit_cast(float, u);
}
static __device__ __forceinline__ bf16 f2bf(float f) {
    unsigned int u = __builtin_bit_cast(unsigned int, f);
    unsigned int r = (u + 0x7fffu + ((u >> 16) & 1u)) >> 16;
    return __builtin_bit_cast(bf16, (unsigned short)r);
}

// ---------------------------------------------------------------------------
// 64-wide generic bf16 MFMA GEMM (kept for init-time folds + fallback path).
// C[M,N] = act(A @ W^T + bias); A in two K-segments; W row-major [N,K].
// Block 256 thr = 4 waves (2x2); tile 32M x 64N. grid = (N/64, M/32).
// ---------------------------------------------------------------------------
template <bool RELU, int K, int SPLITK, int KSTART>
__global__ __launch_bounds__(256) void gemm_kernel(
    const bf16* __restrict__ A0, long lda0,
    const bf16* __restrict__ A1, long lda1,
    const bf16* __restrict__ W, const float* __restrict__ bias,
    float* __restrict__ Cf, long ldc, bf16* __restrict__ Cbf, int ldcbf) {
    const int tid = threadIdx.x;
    const int wave = tid >> 6, lane = tid & 63;
    const int wm = wave >> 1, wn = wave & 1;
    const int quad = lane >> 4, r = lane & 15;
    const int kq = quad * 8;

    const int m0 = blockIdx.y * 32 + wm * 16 + r;
    const int n0 = blockIdx.x * 64 + wn * 32;

    const bf16* a0row = A0 + (long)m0 * lda0;
    const bf16* a1row = A1 + (long)m0 * lda1;
    const bf16* w0 = W + (long)(n0 + r) * K;
    const bf16* w1 = W + (long)(n0 + 16 + r) * K;

    f32x4 acc0 = {0.f, 0.f, 0.f, 0.f}, acc1 = {0.f, 0.f, 0.f, 0.f};

    for (int k0 = KSTART; k0 < K; k0 += 32) {
        bf16x8 av;
        if (k0 < SPLITK)
            av = *(const bf16x8*)(a0row + k0 + kq);
        else
            av = *(const bf16x8*)(a1row + (k0 - SPLITK) + kq);
        bf16x8 bv0 = *(const bf16x8*)(w0 + k0 + kq);
        bf16x8 bv1 = *(const bf16x8*)(w1 + k0 + kq);
        acc0 = __builtin_amdgcn_mfma_f32_16x16x32_bf16(av, bv0, acc0, 0, 0, 0);
        acc1 = __builtin_amdgcn_mfma_f32_16x16x32_bf16(av, bv1, acc1, 0, 0, 0);
    }

    const int mbase = blockIdx.y * 32 + wm * 16 + quad * 4;
    const int nA = n0 + r, nB = n0 + 16 + r;
    const float biasA = bias[nA], biasB = bias[nB];
#pragma unroll
    for (int reg = 0; reg < 4; ++reg) {
        const int m = mbase + reg;
        float vA = acc0[reg] + biasA;
        float vB = acc1[reg] + biasB;
        if (RELU) { vA = fmaxf(vA, 0.f); vB = fmaxf(vB, 0.f); }
        if (Cf) {
            Cf[(long)m * ldc + nA] = vA;
            Cf[(long)m * ldc + nB] = vB;
        }
        if (Cbf) {
            Cbf[(long)m * ldcbf + nA] = f2bf(vA);
            Cbf[(long)m * ldcbf + nB] = f2bf(vB);
        }
    }
}

// ---------------------------------------------------------------------------
// 32-wide GEMM for the per-step combine: tile 32M x 32N, wave tile 16x16,
// grid = (N/32, M/32) = 512 blocks -> 2 blocks/CU (2 waves/SIMD TLP).
// ---------------------------------------------------------------------------
template <bool RELU, int K, int SPLITK, int KSTART>
__global__ __launch_bounds__(256) void gemm32_kernel(
    const bf16* __restrict__ A0, long lda0,
    const bf16* __restrict__ A1, long lda1,
    const bf16* __restrict__ W, const float* __restrict__ bias,
    float* __restrict__ Cf, long ldc, bf16* __restrict__ Cbf, int ldcbf) {
    const int tid = threadIdx.x;
    const int wave = tid >> 6, lane = tid & 63;
    const int wm = wave >> 1, wn = wave & 1;
    const int quad = lane >> 4, r = lane & 15;
    const int kq = quad * 8;

    const int m0 = blockIdx.y * 32 + wm * 16 + r;
    const int n0 = blockIdx.x * 32 + wn * 16;

    const bf16* a0row = A0 + (long)m0 * lda0;
    const bf16* a1row = A1 + (long)m0 * lda1;
    const bf16* w0 = W + (long)(n0 + r) * K;

    f32x4 acc0 = {0.f, 0.f, 0.f, 0.f};

    for (int k0 = KSTART; k0 < K; k0 += 32) {
        bf16x8 av;
        if (k0 < SPLITK)
            av = *(const bf16x8*)(a0row + k0 + kq);
        else
            av = *(const bf16x8*)(a1row + (k0 - SPLITK) + kq);
        bf16x8 bv0 = *(const bf16x8*)(w0 + k0 + kq);
        acc0 = __builtin_amdgcn_mfma_f32_16x16x32_bf16(av, bv0, acc0, 0, 0, 0);
    }

    const int mbase = blockIdx.y * 32 + wm * 16 + quad * 4;
    const int nA = n0 + r;
    const float biasA = bias[nA];
#pragma unroll
    for (int reg = 0; reg < 4; ++reg) {
        const int m = mbase + reg;
        float vA = acc0[reg] + biasA;
        if (RELU) vA = fmaxf(vA, 0.f);
        if (Cf) Cf[(long)m * ldc + nA] = vA;
        if (Cbf) Cbf[(long)m * ldcbf + nA] = f2bf(vA);
    }
}

// ---------------------------------------------------------------------------
// Batched fc_out over the whole h history: rows m = t*B + b of Hh[T*B, H],
// out[b, t, n] = Hh[m] @ Wo^T + bo.  grid = (16, T*B/32).
// ---------------------------------------------------------------------------
__global__ __launch_bounds__(256) void fcout_batch_kernel(
    const bf16* __restrict__ Hh, const bf16* __restrict__ Wo,
    const float* __restrict__ bo, float* __restrict__ out) {
    const int tid = threadIdx.x;
    const int wave = tid >> 6, lane = tid & 63;
    const int wm = wave >> 1, wn = wave & 1;
    const int quad = lane >> 4, r = lane & 15;
    const int kq = quad * 8;

    const int m0 = blockIdx.y * 32 + wm * 16 + r;
    const int n0 = blockIdx.x * 64 + wn * 32;

    const bf16* arow = Hh + (long)m0 * H;
    const bf16* w0 = Wo + (long)(n0 + r) * H;
    const bf16* w1 = Wo + (long)(n0 + 16 + r) * H;

    f32x4 acc0 = {0.f, 0.f, 0.f, 0.f}, acc1 = {0.f, 0.f, 0.f, 0.f};
    for (int k0 = 0; k0 < H; k0 += 32) {
        bf16x8 av = *(const bf16x8*)(arow + k0 + kq);
        bf16x8 bv0 = *(const bf16x8*)(w0 + k0 + kq);
        bf16x8 bv1 = *(const bf16x8*)(w1 + k0 + kq);
        acc0 = __builtin_amdgcn_mfma_f32_16x16x32_bf16(av, bv0, acc0, 0, 0, 0);
        acc1 = __builtin_amdgcn_mfma_f32_16x16x32_bf16(av, bv1, acc1, 0, 0, 0);
    }

    const int mbase = blockIdx.y * 32 + wm * 16 + quad * 4;
    const int nA = n0 + r, nB = n0 + 16 + r;
    const float biasA = bo[nA], biasB = bo[nB];
#pragma unroll
    for (int reg = 0; reg < 4; ++reg) {
        const int m = mbase + reg;
        const int b = m & (B - 1);
        const int tt = m >> 9;  // B = 512
        float* orow = out + (long)b * ((long)T * O) + (long)tt * O;
        orow[nA] = acc0[reg] + biasA;
        orow[nB] = acc1[reg] + biasB;
    }
}

// ---------------------------------------------------------------------------
// Fused attention: logits (VALU fp32 dot) + softmax + apply, one block per
// batch row.  grid = B.  Wlog [64,1024] row-major (128 KB, L2-hot).
// h row staged in LDS with 4-word skew per 256-word segment so the four
// k-partition broadcast groups land in distinct banks.
// ---------------------------------------------------------------------------
#define HIDX(k) ((k) + (((k) >> 8) << 2))
__global__ __launch_bounds__(256) void attn_fused_kernel(
    const bf16* __restrict__ h, const bf16* __restrict__ Wlog,
    const float* __restrict__ bvec, const bf16* __restrict__ enc,
    bf16* __restrict__ attn_out) {
    __shared__ float hsh[1040];
    __shared__ float lg[64];
    __shared__ float wbuf[64];
    const int b = blockIdx.x;
    const int tid = threadIdx.x;

    // stage h row (2 KB) into LDS as fp32
    {
        const int k = tid * 4;
        bf16x4 v = *(const bf16x4*)(h + (long)b * H + k);
        float4 f = {bf2f(v[0]), bf2f(v[1]), bf2f(v[2]), bf2f(v[3])};
        *(float4*)&hsh[HIDX(k)] = f;
    }
    __syncthreads();

    // phase 1: logits.  thread t: s = t>>2, k-partition = t&3 (256 k each)
    {
        const int s = tid >> 2, kpart = tid & 3;
        const bf16* wrow = Wlog + (long)s * 1024 + kpart * 256;
        const int kb = kpart * 256;
        float acc = 0.f;
#pragma unroll
        for (int i = 0; i < 32; ++i) {
            bf16x8 wv = *(const bf16x8*)(wrow + i * 8);
            const float4 ha = *(const float4*)&hsh[HIDX(kb + i * 8)];
            const float4 hb = *(const float4*)&hsh[HIDX(kb + i * 8 + 4)];
            acc += bf2f(wv[0]) * ha.x + bf2f(wv[1]) * ha.y +
                   bf2f(wv[2]) * ha.z + bf2f(wv[3]) * ha.w +
                   bf2f(wv[4]) * hb.x + bf2f(wv[5]) * hb.y +
                   bf2f(wv[6]) * hb.z + bf2f(wv[7]) * hb.w;
        }
        acc += __shfl_xor(acc, 1);
        acc += __shfl_xor(acc, 2);
        if (kpart == 0) lg[s] = acc + bvec[s];
    }
    __syncthreads();

    // phase 2: softmax over 64 logits (wave 0)
    if (tid < 64) {
        const float v = lg[tid];
        float mx = v;
#pragma unroll
        for (int off = 32; off; off >>= 1) mx = fmaxf(mx, __shfl_xor(mx, off));
        const float e = __expf(v - mx);
        float sum = e;
#pragma unroll
        for (int off = 32; off; off >>= 1) sum += __shfl_xor(sum, off);
        wbuf[tid] = e / sum;
    }
    __syncthreads();

    // phase 3: apply.  thread t covers d = 4t..4t+3, non-temporal enc stream
    const bf16* e = enc + (long)b * (S * 1024) + tid * 4;
    float a0 = 0.f, a1 = 0.f, a2 = 0.f, a3 = 0.f;
#pragma unroll 16
    for (int s2 = 0; s2 < S; ++s2) {
        unsigned long long raw =
            __builtin_nontemporal_load((const unsigned long long*)(e + (long)s2 * 1024));
        bf16x4 v = __builtin_bit_cast(bf16x4, raw);
        const float ws = wbuf[s2];
        a0 += ws * bf2f(v[0]);
        a1 += ws * bf2f(v[1]);
        a2 += ws * bf2f(v[2]);
        a3 += ws * bf2f(v[3]);
    }
    bf16x4 o = {f2bf(a0), f2bf(a1), f2bf(a2), f2bf(a3)};
    *(bf16x4*)(attn_out + (long)b * 1024 + tid * 4) = o;
}

// ---------------------------------------------------------------------------
// Fused GRU, 32x32 tiles: 6 simultaneous GEMM accumulations + gates + h_new.
// grid = (H/32, B/32) = 512 blocks -> 2 blocks/CU.
// ---------------------------------------------------------------------------
__global__ __launch_bounds__(256) void gru32_kernel(
    const bf16* __restrict__ gin, const bf16* __restrict__ hbf,
    const bf16* __restrict__ Wih, const bf16* __restrict__ Whh,
    const float* __restrict__ bih, const float* __restrict__ bhh,
    const float* __restrict__ hold, float* __restrict__ hnew,
    bf16* __restrict__ hnewbf) {
    const int tid = threadIdx.x;
    const int wave = tid >> 6, lane = tid & 63;
    const int wm = wave >> 1, wn = wave & 1;
    const int quad = lane >> 4, r = lane & 15;
    const int kq = quad * 8;

    const int m0 = blockIdx.y * 32 + wm * 16 + r;
    const int n0 = blockIdx.x * 32 + wn * 16;

    const bf16* grow = gin + (long)m0 * H;
    const bf16* hrow = hbf + (long)m0 * H;

    const bf16* wi[3];
    const bf16* wh[3];
#pragma unroll
    for (int g = 0; g < 3; ++g) {
        const long row = (long)g * H + n0 + r;
        wi[g] = Wih + row * H;
        wh[g] = Whh + row * H;
    }

    f32x4 aI[3], aH[3];
#pragma unroll
    for (int g = 0; g < 3; ++g) {
        aI[g] = (f32x4){0.f, 0.f, 0.f, 0.f};
        aH[g] = (f32x4){0.f, 0.f, 0.f, 0.f};
    }

    for (int k0 = 0; k0 < H; k0 += 32) {
        const int ko = k0 + kq;
        bf16x8 ai = *(const bf16x8*)(grow + ko);
        bf16x8 ah = *(const bf16x8*)(hrow + ko);
#pragma unroll
        for (int g = 0; g < 3; ++g) {
            bf16x8 bi = *(const bf16x8*)(wi[g] + ko);
            aI[g] = __builtin_amdgcn_mfma_f32_16x16x32_bf16(ai, bi, aI[g], 0, 0, 0);
            bf16x8 bh = *(const bf16x8*)(wh[g] + ko);
            aH[g] = __builtin_amdgcn_mfma_f32_16x16x32_bf16(ah, bh, aH[g], 0, 0, 0);
        }
    }

    const int mbase = blockIdx.y * 32 + wm * 16 + quad * 4;
    const int j = n0 + r;
    const float bir = bih[j], biz = bih[j + H], bin = bih[j + 2 * H];
    const float bhr = bhh[j], bhz = bhh[j + H], bhn = bhh[j + 2 * H];
#pragma unroll
    for (int reg = 0; reg < 4; ++reg) {
        const int m = mbase + reg;
        const float gir = aI[0][reg] + bir, ghr = aH[0][reg] + bhr;
        const float giz = aI[1][reg] + biz, ghz = aH[1][reg] + bhz;
        const float ginv = aI[2][reg] + bin, ghn = aH[2][reg] + bhn;
        const float rg = 1.f / (1.f + __expf(-(gir + ghr)));
        const float zg = 1.f / (1.f + __expf(-(giz + ghz)));
        const float ng = tanhf(ginv + rg * ghn);
        const long idx = (long)m * H + j;
        const float hv = hold[idx];
        const float hnv = (1.f - zg) * ng + zg * hv;
        hnew[idx] = hnv;
        hnewbf[idx] = f2bf(hnv);
    }
}

// ---------------------------------------------------------------------------
// init / precompute kernels
// ---------------------------------------------------------------------------
__global__ __launch_bounds__(256) void cast2d_kernel(
    const float* __restrict__ src, long ld_src, long soff,
    bf16* __restrict__ dst, long ld_dst, long doff, long rows, long cols4) {
    const long total = rows * cols4;
    const long stride = (long)gridDim.x * blockDim.x;
    for (long i = (long)blockIdx.x * blockDim.x + threadIdx.x; i < total; i += stride) {
        const long rr = i / cols4;
        const long c = (i - rr * cols4) << 2;
        const float4 v = *(const float4*)(src + rr * ld_src + soff + c);
        bf16x4 o = {f2bf(v.x), f2bf(v.y), f2bf(v.z), f2bf(v.w)};
        *(bf16x4*)(dst + rr * ld_dst + doff + c) = o;
    }
}

__global__ __launch_bounds__(256) void transpose_cast_kernel(
    const float* __restrict__ src, bf16* __restrict__ dst, int n) {
    __shared__ float tile[32][33];
    const int tx = threadIdx.x & 31, ty = threadIdx.x >> 5;
    const int x0 = blockIdx.x * 32, y0 = blockIdx.y * 32;
#pragma unroll
    for (int i = 0; i < 32; i += 8)
        tile[ty + i][tx] = src[(long)(y0 + ty + i) * n + x0 + tx];
    __syncthreads();
#pragma unroll
    for (int i = 0; i < 32; i += 8)
        dst[(long)(x0 + ty + i) * n + y0 + tx] = f2bf(tile[tx][ty + i]);
}

__global__ __launch_bounds__(256) void addcast_wlog_kernel(
    const float* __restrict__ P1, const float* __restrict__ Wa,
    bf16* __restrict__ Wlog1) {
    const int i = blockIdx.x * 256 + threadIdx.x;
    if (i < 64 * 1024) {
        const int rr = i >> 10, c = i & 1023;
        Wlog1[i] = f2bf(P1[i] + Wa[(long)rr * 2048 + 1024 + c]);
    }
}

__global__ __launch_bounds__(256) void bias_fuse_kernel(
    const float* __restrict__ W, long ld, const float* __restrict__ v,
    const float* __restrict__ b_in, float* __restrict__ b_out) {
    __shared__ float red[256];
    const int r = blockIdx.x, tid = threadIdx.x;
    float s = 0.f;
    for (int j = tid; j < 1024; j += 256) s += W[(long)r * ld + j] * v[j];
    red[tid] = s;
    __syncthreads();
    for (int off = 128; off > 0; off >>= 1) {
        if (tid < off) red[tid] += red[tid + off];
        __syncthreads();
    }
    if (tid == 0) b_out[r] = b_in[r] + red[0];
}

__global__ __launch_bounds__(256) void init_h_kernel(
    const float* __restrict__ h0, float* __restrict__ hfp,
    bf16* __restrict__ hbf, long n4) {
    long i = (long)blockIdx.x * blockDim.x + threadIdx.x;
    const long stride = (long)gridDim.x * blockDim.x;
    for (; i < n4; i += stride) {
        float4 v = ((const float4*)h0)[i];
        ((float4*)hfp)[i] = v;
        bf16x4 o = {f2bf(v.x), f2bf(v.y), f2bf(v.z), f2bf(v.w)};
        *(bf16x4*)(hbf + 4 * i) = o;
    }
}

__global__ __launch_bounds__(256) void copy_f32_kernel(
    const float* __restrict__ src, float* __restrict__ dst, long n4) {
    long i = (long)blockIdx.x * blockDim.x + threadIdx.x;
    const long stride = (long)gridDim.x * blockDim.x;
    for (; i < n4; i += stride) ((float4*)dst)[i] = ((const float4*)src)[i];
}

// ---------------------------------------------------------------------------
extern "C" void kernel_launch(void* const* d_in, const int* in_sizes, int n_in,
                              void* d_out, int out_size, void* d_ws, size_t ws_size,
                              hipStream_t stream) {
    const float* enc_f = (const float*)d_in[0];
    const float* hidden = (const float*)d_in[1];
    // d_in[2] = max_length (always 128 here)
    const float* Wa = (const float*)d_in[3];
    const float* ba = (const float*)d_in[4];
    const float* Wc = (const float*)d_in[5];
    const float* bc = (const float*)d_in[6];
    const float* Wih = (const float*)d_in[7];
    const float* Whh = (const float*)d_in[8];
    const float* bih = (const float*)d_in[9];
    const float* bhh = (const float*)d_in[10];
    const float* Wo = (const float*)d_in[11];
    const float* bo = (const float*)d_in[12];
    float* out = (float*)d_out;

    // ---- workspace carve-up ----
    char* p = (char*)d_ws;
    auto carve = [&](long bytes) {
        char* q = p;
        p += (bytes + 255) & ~255L;
        return q;
    };
    bf16* Wlog0 = (bf16*)carve((long)64 * 1024 * 2);        // Wa_h (t=0 logits)
    bf16* Wlog1 = (bf16*)carve((long)64 * 1024 * 2);        // Wa_d@Wo + Wa_h
    bf16* Wcomb = (bf16*)carve((long)H * 2048 * 2);         // [Wc_d@Wo | Wc_a]
    bf16* Wih_bf = (bf16*)carve((long)3 * H * H * 2);
    bf16* Whh_bf = (bf16*)carve((long)3 * H * H * 2);
    bf16* Wo_bf = (bf16*)carve((long)O * H * 2);
    bf16* enc_bf = (bf16*)carve((long)B * S * 1024 * 2);    // also init scratch
    bf16* attn_bf = (bf16*)carve((long)B * 1024 * 2);
    bf16* gru_bf = (bf16*)carve((long)B * H * 2);
    bf16* h0bf = (bf16*)carve((long)B * H * 2);
    bf16* hbfA = (bf16*)carve((long)B * H * 2);             // fallback h slots
    bf16* hbfB = (bf16*)carve((long)B * H * 2);
    float* hfpA = (float*)carve((long)B * H * 4);
    float* hfpB = (float*)carve((long)B * H * 4);
    float* blog1 = (float*)carve(64 * 4);
    float* bc2 = (float*)carve((long)H * 4);
    float* zeros = (float*)carve(1024 * 4);

    const long persistent = (long)(p - (char*)d_ws);
    const long histBytes = (long)T * B * H * 2;  // 128 MB bf16 h history
    const bool batched = (ws_size >= (size_t)(persistent + histBytes + 256));
    bf16* hist = batched ? (bf16*)carve(histBytes) : nullptr;
    auto slot = [&](int t2) -> bf16* {
        return batched ? hist + (long)t2 * ((long)B * H)
                       : ((t2 & 1) ? hbfB : hbfA);
    };

    // ---- init-time scratch aliased into enc_bf (consumed before enc cast) ----
    {
        char* sp = (char*)enc_bf;
        auto scarve = [&](long bytes) {
            char* q = sp;
            sp += (bytes + 255) & ~255L;
            return q;
        };
        bf16* Wad = (bf16*)scarve((long)64 * 1024 * 2);
        bf16* Wcd = (bf16*)scarve((long)H * 1024 * 2);
        bf16* WoT = (bf16*)scarve((long)H * O * 2);
        float* P1 = (float*)scarve((long)64 * 1024 * 4);
        float* P2 = (float*)scarve((long)H * 1024 * 4);

        hipMemsetAsync(zeros, 0, 1024 * 4, stream);

        auto cast2d = [&](const float* src, long lds_, long so, bf16* dst,
                          long ldd, long doff, long rows, long cols) {
            long n4 = rows * (cols / 4);
            int blocks = (int)((n4 + 255) / 256);
            if (blocks > 4096) blocks = 4096;
            cast2d_kernel<<<blocks, 256, 0, stream>>>(src, lds_, so, dst, ldd,
                                                      doff, rows, cols / 4);
        };
        cast2d(Wa, 2048, 1024, Wlog0, 1024, 0, 64, 1024);       // Wa_h
        cast2d(Wa, 2048, 0, Wad, 1024, 0, 64, 1024);            // Wa_d
        cast2d(Wc, 2048, 0, Wcd, 1024, 0, 1024, 1024);          // Wc_d
        cast2d(Wc, 2048, 1024, Wcomb, 2048, 1024, 1024, 1024);  // Wc_a half
        cast2d(Wih, 1024, 0, Wih_bf, 1024, 0, 3 * H, 1024);
        cast2d(Whh, 1024, 0, Whh_bf, 1024, 0, 3 * H, 1024);
        cast2d(Wo, 1024, 0, Wo_bf, 1024, 0, O, 1024);
        transpose_cast_kernel<<<dim3(32, 32), 256, 0, stream>>>(Wo, WoT, 1024);

        // P1 = Wa_d @ Wo ; P2 = Wc_d @ Wo   (WoT is [N,K])
        gemm_kernel<false, 1024, 1024, 0><<<dim3(16, 2), 256, 0, stream>>>(
            Wad, 1024, Wad, 1024, WoT, zeros, P1, 1024, nullptr, 0);
        gemm_kernel<false, 1024, 1024, 0><<<dim3(16, 32), 256, 0, stream>>>(
            Wcd, 1024, Wcd, 1024, WoT, zeros, P2, 1024, nullptr, 0);

        addcast_wlog_kernel<<<256, 256, 0, stream>>>(P1, Wa, Wlog1);
        cast2d(P2, 1024, 0, Wcomb, 2048, 0, 1024, 1024);        // Wxc half

        bias_fuse_kernel<<<64, 256, 0, stream>>>(Wa, 2048, bo, ba, blog1);
        bias_fuse_kernel<<<1024, 256, 0, stream>>>(Wc, 2048, bo, bc, bc2);

        // scratch consumed -> now cast enc over it
        cast2d(enc_f, 1024, 0, enc_bf, 1024, 0, (long)B * S, 1024);
        init_h_kernel<<<512, 256, 0, stream>>>(hidden, hfpA, h0bf, (long)B * H / 4);
    }

    const dim3 blk(256);
    const dim3 grid32(H / 32, B / 32);  // (32,16) = 512 blocks
    const dim3 grid64(H / 64, B / 32);  // fallback fc_out

    for (int t = 0; t < T; ++t) {
        const bf16* h_in = (t == 0) ? h0bf : slot(t - 1);
        bf16* h_out = slot(t);
        const float* hfp_r = (t & 1) ? hfpB : hfpA;
        float* hfp_w = (t & 1) ? hfpA : hfpB;

        // 1) fused attention: logits (Wo folded for t>=1) + softmax + apply
        attn_fused_kernel<<<B, blk, 0, stream>>>(
            h_in, t ? Wlog1 : Wlog0, t ? blog1 : ba, enc_bf, attn_bf);
        // 2) combine + relu -> gru_in.  t=0: dec==0 -> skip h-segment, orig bias
        if (t == 0)
            gemm32_kernel<true, 2048, 1024, 1024><<<grid32, blk, 0, stream>>>(
                h_in, 1024, attn_bf, 1024, Wcomb, bc, nullptr, 0, gru_bf, H);
        else
            gemm32_kernel<true, 2048, 1024, 0><<<grid32, blk, 0, stream>>>(
                h_in, 1024, attn_bf, 1024, Wcomb, bc2, nullptr, 0, gru_bf, H);
        // 3) fused GRU -> h_new (fp32 ping-pong + bf16 history slot)
        gru32_kernel<<<grid32, blk, 0, stream>>>(
            gru_bf, h_in, Wih_bf, Whh_bf, bih, bhh, hfp_r, hfp_w, h_out);
        // 4) fc_out only if we cannot batch it (workspace too small)
        if (!batched)
            gemm_kernel<false, 1024, 1024, 0><<<grid64, blk, 0, stream>>>(
                h_out, 1024, h_out, 1024, Wo_bf, bo,
                out + (long)t * O, (long)T * O, nullptr, 0);
    }

    // batched fc_out over the whole history: one big GEMM off the critical path
    if (batched)
        fcout_batch_kernel<<<dim3(16, (T * B) / 32), blk, 0, stream>>>(
            hist, Wo_bf, bo, out);

    // final hidden (t=127 wrote hfpA) -> tail of d_out
    copy_f32_kernel<<<512, 256, 0, stream>>>(hfpA, out + (long)B * T * O,
                                             (long)B * H / 4);
}